// Round 1
// baseline (351.002 us; speedup 1.0000x reference)
//
#include <hip/hip_runtime.h>

// out[b] = (1/16) * sum_{n,s} inputs[b,n,s] * centroids[n,s]
// inputs: [B=32768, 16, 128] fp32 (row = 2048 contiguous floats)
// centroids: [16, 128] fp32 (2048 floats, broadcast to all rows)
// Memory-bound: 256 MiB read -> stage centroids in LDS, one wave per row,
// 8x float4 loads/lane (coalesced), wave shuffle reduction.

#define BLOCK 256
#define WAVES_PER_BLOCK (BLOCK / 64)
#define ROW_F4 512  // 2048 floats = 512 float4 per row

__global__ __launch_bounds__(BLOCK) void bins_combiner_kernel(
    const float4* __restrict__ in,      // [B * 512] float4
    const float4* __restrict__ cent,    // [512] float4
    float* __restrict__ out,            // [B]
    int B) {
    __shared__ float4 c_lds[ROW_F4];  // 8 KiB centroid table

    // Cooperative stage of centroids into LDS (coalesced, once per block).
    for (int i = threadIdx.x; i < ROW_F4; i += BLOCK) {
        c_lds[i] = cent[i];
    }
    __syncthreads();

    const int wave = threadIdx.x >> 6;
    const int lane = threadIdx.x & 63;
    const int waves_total = gridDim.x * WAVES_PER_BLOCK;

    for (int row = blockIdx.x * WAVES_PER_BLOCK + wave; row < B;
         row += waves_total) {
        const float4* rp = in + (size_t)row * ROW_F4;

        float acc = 0.0f;
#pragma unroll
        for (int k = 0; k < 8; ++k) {
            const int idx = k * 64 + lane;   // lane-contiguous -> coalesced
            const float4 a = rp[idx];
            const float4 c = c_lds[idx];
            acc += a.x * c.x + a.y * c.y + a.z * c.z + a.w * c.w;
        }

        // Wave-wide sum over 64 lanes.
#pragma unroll
        for (int off = 32; off > 0; off >>= 1) {
            acc += __shfl_down(acc, off, 64);
        }
        if (lane == 0) {
            out[row] = acc * (1.0f / 16.0f);
        }
    }
}

extern "C" void kernel_launch(void* const* d_in, const int* in_sizes, int n_in,
                              void* d_out, int out_size, void* d_ws, size_t ws_size,
                              hipStream_t stream) {
    const float4* in = (const float4*)d_in[0];      // [B,16,128] fp32
    const float4* cent = (const float4*)d_in[1];    // [16,128] fp32
    float* out = (float*)d_out;                     // [B] fp32

    const int B = out_size;  // 32768
    const int rows_per_block = WAVES_PER_BLOCK;
    const int grid = (B + rows_per_block - 1) / rows_per_block;  // 8192

    bins_combiner_kernel<<<grid, BLOCK, 0, stream>>>(in, cent, out, B);
}

// Round 3
// 330.057 us; speedup vs baseline: 1.0635x; 1.0635x over previous
//
#include <hip/hip_runtime.h>

// out[b] = (1/16) * sum_{n,s} inputs[b,n,s] * centroids[n,s]
// inputs: [B=32768, 16, 128] fp32 (row = 2048 contiguous floats = 512 float4)
// centroids: [16, 128] fp32, broadcast to all rows.
//
// Memory-bound streaming GEMV (268 MB @ ~6.3 TB/s -> ~43 us floor).
// Design: persistent waves, centroid fragment (8 x fv4 per lane, fixed
// across rows) held in REGISTERS -- no LDS, no __syncthreads, no block
// churn. 2-row software pipeline = 16 nontemporal 16B loads in flight
// per wave.

typedef float fv4 __attribute__((ext_vector_type(4)));  // native clang vector
                                                        // (nontemporal-load OK)

#define BLOCK 256
#define WAVES_PER_BLOCK (BLOCK / 64)
#define ROW_F4 512          // 512 x 16B per row
#define GRID 2048           // 8 blocks/CU * 256 CUs -> 8192 persistent waves

__global__ __launch_bounds__(BLOCK) void bins_combiner_kernel(
    const fv4* __restrict__ in,      // [B * 512]
    const fv4* __restrict__ cent,    // [512]
    float* __restrict__ out,         // [B]
    int B) {
    const int lane = threadIdx.x & 63;
    const int wave_id = blockIdx.x * WAVES_PER_BLOCK + (threadIdx.x >> 6);
    const int waves_total = gridDim.x * WAVES_PER_BLOCK;

    // Per-lane centroid fragment: lane uses only cent[k*64 + lane], k=0..7.
    // 32 floats -> 32 VGPRs, loaded once, reused for every row.
    fv4 c[8];
#pragma unroll
    for (int k = 0; k < 8; ++k) {
        c[k] = cent[k * 64 + lane];
    }

    const int rows_per_wave = (B + waves_total - 1) / waves_total;  // 4
    const int row0 = wave_id * rows_per_wave;
    const int row_end = (row0 + rows_per_wave < B) ? row0 + rows_per_wave : B;

    for (int r = row0; r < row_end; r += 2) {
        const bool has2 = (r + 1) < row_end;
        const int r1 = has2 ? (r + 1) : r;  // clamp (no OOB; B is even anyway)
        const fv4* rp0 = in + (size_t)r * ROW_F4;
        const fv4* rp1 = in + (size_t)r1 * ROW_F4;

        // Issue all 16 loads (2 rows) before any use: max loads-in-flight.
        fv4 a0[8], a1[8];
#pragma unroll
        for (int k = 0; k < 8; ++k) {
            a0[k] = __builtin_nontemporal_load(&rp0[k * 64 + lane]);
        }
#pragma unroll
        for (int k = 0; k < 8; ++k) {
            a1[k] = __builtin_nontemporal_load(&rp1[k * 64 + lane]);
        }

        float acc0 = 0.0f, acc1 = 0.0f;
#pragma unroll
        for (int k = 0; k < 8; ++k) {
            acc0 += a0[k].x * c[k].x + a0[k].y * c[k].y +
                    a0[k].z * c[k].z + a0[k].w * c[k].w;
        }
#pragma unroll
        for (int k = 0; k < 8; ++k) {
            acc1 += a1[k].x * c[k].x + a1[k].y * c[k].y +
                    a1[k].z * c[k].z + a1[k].w * c[k].w;
        }

        // Wave-wide sums over 64 lanes (two independent reductions).
#pragma unroll
        for (int off = 32; off > 0; off >>= 1) {
            acc0 += __shfl_down(acc0, off, 64);
            acc1 += __shfl_down(acc1, off, 64);
        }
        if (lane == 0) {
            out[r] = acc0 * (1.0f / 16.0f);
            if (has2) out[r + 1] = acc1 * (1.0f / 16.0f);
        }
    }
}

extern "C" void kernel_launch(void* const* d_in, const int* in_sizes, int n_in,
                              void* d_out, int out_size, void* d_ws, size_t ws_size,
                              hipStream_t stream) {
    const fv4* in = (const fv4*)d_in[0];      // [B,16,128] fp32
    const fv4* cent = (const fv4*)d_in[1];    // [16,128] fp32
    float* out = (float*)d_out;               // [B] fp32

    const int B = out_size;  // 32768
    bins_combiner_kernel<<<GRID, BLOCK, 0, stream>>>(in, cent, out, B);
}

// Round 4
// 329.259 us; speedup vs baseline: 1.0660x; 1.0024x over previous
//
#include <hip/hip_runtime.h>

// out[b] = (1/16) * sum_{n,s} inputs[b,n,s] * centroids[n,s]
// inputs: [B=32768, 16, 128] fp32 (row = 2048 contiguous floats = 512x16B)
// centroids: [16, 128] fp32, broadcast to all rows.
//
// Memory-bound streaming GEMV: 268.5 MB mandatory traffic @ ~6.5 TB/s
// -> ~41 us floor. Design: one fully-unrolled step per wave -- 4 rows,
// 32 nontemporal 16B loads in flight, centroid fragment in registers,
// four independent shuffle reductions, one float4 output store.

typedef float fv4 __attribute__((ext_vector_type(4)));

#define BLOCK 256
#define WAVES_PER_BLOCK (BLOCK / 64)
#define ROW_F4 512          // 512 x 16B per row
#define GRID 2048           // 8192 waves x 4 rows = 32768 rows

__global__ __launch_bounds__(BLOCK) void bins_combiner_kernel(
    const fv4* __restrict__ in,      // [B * 512]
    const fv4* __restrict__ cent,    // [512]
    float4* __restrict__ out4,       // [B/4]
    int B) {
    const int lane = threadIdx.x & 63;
    const int wave_id = blockIdx.x * WAVES_PER_BLOCK + (threadIdx.x >> 6);

    // 4 consecutive rows per wave, one unrolled step.
    const int r0 = wave_id * 4;
    if (r0 >= B) return;

    const fv4* rp = in + (size_t)r0 * ROW_F4;

    // Issue all 32 row loads first (max loads in flight), then the 8
    // centroid loads (L2-resident after first blocks).
    fv4 a[4][8];
#pragma unroll
    for (int rr = 0; rr < 4; ++rr) {
#pragma unroll
        for (int k = 0; k < 8; ++k) {
            a[rr][k] =
                __builtin_nontemporal_load(&rp[rr * ROW_F4 + k * 64 + lane]);
        }
    }

    fv4 c[8];
#pragma unroll
    for (int k = 0; k < 8; ++k) {
        c[k] = cent[k * 64 + lane];
    }

    float acc[4];
#pragma unroll
    for (int rr = 0; rr < 4; ++rr) {
        float s = 0.0f;
#pragma unroll
        for (int k = 0; k < 8; ++k) {
            s += a[rr][k].x * c[k].x + a[rr][k].y * c[k].y +
                 a[rr][k].z * c[k].z + a[rr][k].w * c[k].w;
        }
        acc[rr] = s;
    }

    // Four independent 64-lane shuffle reductions.
#pragma unroll
    for (int off = 32; off > 0; off >>= 1) {
#pragma unroll
        for (int rr = 0; rr < 4; ++rr) {
            acc[rr] += __shfl_down(acc[rr], off, 64);
        }
    }

    if (lane == 0) {
        float4 o;
        o.x = acc[0] * (1.0f / 16.0f);
        o.y = acc[1] * (1.0f / 16.0f);
        o.z = acc[2] * (1.0f / 16.0f);
        o.w = acc[3] * (1.0f / 16.0f);
        out4[wave_id] = o;
    }
}

extern "C" void kernel_launch(void* const* d_in, const int* in_sizes, int n_in,
                              void* d_out, int out_size, void* d_ws, size_t ws_size,
                              hipStream_t stream) {
    const fv4* in = (const fv4*)d_in[0];      // [B,16,128] fp32
    const fv4* cent = (const fv4*)d_in[1];    // [16,128] fp32
    float4* out4 = (float4*)d_out;            // [B] fp32, written as float4

    const int B = out_size;  // 32768
    bins_combiner_kernel<<<GRID, BLOCK, 0, stream>>>(in, cent, out4, B);
}